// Round 6
// baseline (297.109 us; speedup 1.0000x reference)
//
#include <hip/hip_runtime.h>
#include <hip/hip_bf16.h>

// 2-NN: out[q] = sum of 2 smallest ||q - t||^2 over 200000 train points.
// d2 = q_sq + t_sq - 2*q.t ; top-2 depends only on s = t_sq - 2*q.t.
// v6: BARRIER-FREE streaming. r5 proved the XCD remap makes each chunk
//     L2-resident (FETCH 204->28 MB), so LDS staging is pure overhead.
//     Each wave streams B-frags straight from global with a depth-2
//     register pipeline (named sets pA/pB); queries pre-scaled by -2;
//     t_sq injected via MFMA C-in. No LDS, no __syncthreads in knn_main.

typedef short bf16x8 __attribute__((ext_vector_type(8)));   // 8 bf16 = 4 VGPRs
typedef float f32x4 __attribute__((ext_vector_type(4)));

#define N_TRAIN 200000
#define M_QUERY 2048
#define DIMS 128

__device__ __forceinline__ unsigned int bf_bits(float f) {
  unsigned int u = __float_as_uint(f);
  return (u + 0x7FFFu + ((u >> 16) & 1u)) >> 16;
}

// 8 lanes per row; each lane handles 16 contiguous floats (64B) -> coalesced.
// dst holds bf16(scale * src); sq holds exact fp32 ||row||^2 of UNSCALED src.
__global__ __launch_bounds__(256) void convert_kernel(
    const float* __restrict__ src, unsigned short* __restrict__ dst,
    float* __restrict__ sq, int nrows, float scale) {
  int gtid = blockIdx.x * 256 + threadIdx.x;
  int row = gtid >> 3, sub = gtid & 7;
  if (row >= nrows) return;
  const float4* s4 = reinterpret_cast<const float4*>(src + (size_t)row * DIMS + sub * 16);
  unsigned int pk[8];
  float acc = 0.f;
#pragma unroll
  for (int i = 0; i < 4; ++i) {
    float4 v = s4[i];
    acc += v.x * v.x + v.y * v.y + v.z * v.z + v.w * v.w;
    pk[i * 2 + 0] = bf_bits(v.x * scale) | (bf_bits(v.y * scale) << 16);
    pk[i * 2 + 1] = bf_bits(v.z * scale) | (bf_bits(v.w * scale) << 16);
  }
  uint4* d4 = reinterpret_cast<uint4*>(dst + (size_t)row * DIMS + sub * 16);
  d4[0] = make_uint4(pk[0], pk[1], pk[2], pk[3]);
  d4[1] = make_uint4(pk[4], pk[5], pk[6], pk[7]);
  acc += __shfl_xor(acc, 1);
  acc += __shfl_xor(acc, 2);
  acc += __shfl_xor(acc, 4);
  if (sub == 0) sq[row] = acc;
}

// Main. Block = 4 independent waves; wave owns 64 queries (4 m-tiles of 16)
// and streams the chunk's 16-point steps from global (L2-resident via remap).
// Block remap: xcd = b&7 (HW round-robin), all 8 qblocks of a chunk on ONE xcd.
template <int NCH>
__global__ __launch_bounds__(256) void knn_main(
    const unsigned short* __restrict__ tb, const unsigned short* __restrict__ qb16,
    const float* __restrict__ tsq, float* __restrict__ partials) {
  constexpr int PPC = N_TRAIN / NCH;
  constexpr int STEPS = PPC / 16;                // 50 (NCH=250) / 100 (NCH=125)
  const int b = blockIdx.x;
  const int g = (b & 7) * NCH + (b >> 3);        // same-xcd blocks: consecutive g
  const int chunk = g >> 3;
  const int qblock = (g & 7) << 8;
  const int tid = threadIdx.x;
  const int w = tid >> 6, l = tid & 63;
  const int lo = l & 15, hi = l >> 4;
  const int qw = qblock + w * 64;

  // A-fragments (hold -2*q in bf16): Q[qw + t*16 + lo][kf*32 + hi*8 .. +8]
  bf16x8 a[4][4];
#pragma unroll
  for (int t = 0; t < 4; ++t)
#pragma unroll
    for (int kf = 0; kf < 4; ++kf)
      a[t][kf] = *reinterpret_cast<const bf16x8*>(
          qb16 + (size_t)(qw + t * 16 + lo) * DIMS + kf * 32 + hi * 8);

  // B-frag lane address: point lo of the step, bytes kf*64 + hi*16 within row.
  const char* gb = reinterpret_cast<const char*>(tb) +
                   (size_t)chunk * PPC * 256 + lo * 256 + hi * 16;
  const float* tq = tsq + chunk * PPC + lo;

  const float INF = __builtin_inff();
  float best1[4][4], best2[4][4];
#pragma unroll
  for (int t = 0; t < 4; ++t)
#pragma unroll
    for (int r = 0; r < 4; ++r) { best1[t][r] = INF; best2[t][r] = INF; }

#define LOADSET(P, TV, s)                                            \
  do {                                                               \
    const char* _p = gb + (size_t)(s) * 4096;                        \
    P[0] = *reinterpret_cast<const bf16x8*>(_p);                     \
    P[1] = *reinterpret_cast<const bf16x8*>(_p + 64);                \
    P[2] = *reinterpret_cast<const bf16x8*>(_p + 128);               \
    P[3] = *reinterpret_cast<const bf16x8*>(_p + 192);               \
    TV = tq[(s) * 16];                                               \
  } while (0)

#define COMPUTE(P, TV)                                                          \
  do {                                                                          \
    f32x4 c = {TV, TV, TV, TV};                                                 \
    _Pragma("unroll")                                                           \
    for (int t = 0; t < 4; ++t) {                                               \
      f32x4 acc = __builtin_amdgcn_mfma_f32_16x16x32_bf16(a[t][0], P[0], c, 0, 0, 0); \
      acc = __builtin_amdgcn_mfma_f32_16x16x32_bf16(a[t][1], P[1], acc, 0, 0, 0);     \
      acc = __builtin_amdgcn_mfma_f32_16x16x32_bf16(a[t][2], P[2], acc, 0, 0, 0);     \
      acc = __builtin_amdgcn_mfma_f32_16x16x32_bf16(a[t][3], P[3], acc, 0, 0, 0);     \
      _Pragma("unroll")                                                         \
      for (int r = 0; r < 4; ++r) {                                             \
        float s0 = acc[r]; /* = t_sq - 2 q.t (C-in carried t_sq) */             \
        float n1 = fminf(best1[t][r], s0);                                      \
        float n2 = __builtin_amdgcn_fmed3f(best1[t][r], best2[t][r], s0);       \
        best1[t][r] = n1;                                                       \
        best2[t][r] = n2;                                                       \
      }                                                                         \
    }                                                                           \
  } while (0)

  bf16x8 pA[4], pB[4];
  float tvA, tvB;
  LOADSET(pA, tvA, 0);
  LOADSET(pB, tvB, 1);

  int it = 0;
  for (; it + 2 < STEPS; it += 2) {       // modulo-2 schedule, depth-2 prefetch
    COMPUTE(pA, tvA);
    LOADSET(pA, tvA, it + 2);
    COMPUTE(pB, tvB);
    LOADSET(pB, tvB, it + 3);
  }
  COMPUTE(pA, tvA);                       // steps STEPS-2, STEPS-1 (STEPS even)
  COMPUTE(pB, tvB);

#undef LOADSET
#undef COMPUTE

  // merge top-2 across the 16 lanes (columns) sharing each query
#pragma unroll
  for (int t = 0; t < 4; ++t)
#pragma unroll
    for (int r = 0; r < 4; ++r) {
      float v1 = best1[t][r], v2 = best2[t][r];
#pragma unroll
      for (int m = 1; m < 16; m <<= 1) {
        float o1 = __shfl_xor(v1, m);
        float o2 = __shfl_xor(v2, m);
        float n1 = fminf(v1, o1);
        float n2 = fminf(fmaxf(v1, o1), fminf(v2, o2));
        v1 = n1;
        v2 = n2;
      }
      best1[t][r] = v1;
      best2[t][r] = v2;
    }
  if (lo == 0) {
#pragma unroll
    for (int t = 0; t < 4; ++t)
#pragma unroll
      for (int r = 0; r < 4; ++r) {
        int q = qw + t * 16 + hi * 4 + r;
        float* p = partials + ((size_t)chunk * M_QUERY + q) * 2;
        p[0] = best1[t][r];
        p[1] = best2[t][r];
      }
  }
}

__global__ __launch_bounds__(256) void knn_reduce(
    const float* __restrict__ partials, const float* __restrict__ qsq,
    float* __restrict__ out, int nchunk) {
  int q = blockIdx.x * 256 + threadIdx.x;
  if (q >= M_QUERY) return;
  const float INF = __builtin_inff();
  float b1 = INF, b2 = INF;
  for (int c = 0; c < nchunk; ++c) {
    const float* p = partials + ((size_t)c * M_QUERY + q) * 2;
    float v = p[0];
    float n1 = fminf(b1, v);
    float n2 = __builtin_amdgcn_fmed3f(b1, b2, v);
    b1 = n1; b2 = n2;
    v = p[1];
    n1 = fminf(b1, v);
    n2 = __builtin_amdgcn_fmed3f(b1, b2, v);
    b1 = n1; b2 = n2;
  }
  out[q] = 2.f * qsq[q] + b1 + b2;
}

extern "C" void kernel_launch(void* const* d_in, const int* in_sizes, int n_in,
                              void* d_out, int out_size, void* d_ws, size_t ws_size,
                              hipStream_t stream) {
  const float* train = (const float*)d_in[0];  // 200000 x 128 f32
  const float* test  = (const float*)d_in[1];  // 2048 x 128 f32
  float* out = (float*)d_out;                  // 2048 f32
  char* ws = (char*)d_ws;

  size_t off_tb  = 0;                                      // train bf16: 51,200,000 B
  size_t off_qb  = off_tb  + (size_t)N_TRAIN * DIMS * 2;   // query bf16 (-2q)
  size_t off_tsq = off_qb  + (size_t)M_QUERY * DIMS * 2;   // t_sq
  size_t off_qsq = off_tsq + (size_t)N_TRAIN * 4;          // q_sq
  size_t off_pt  = off_qsq + (size_t)M_QUERY * 4;          // partials
  size_t need250 = off_pt + (size_t)250 * M_QUERY * 2 * 4;
  size_t need125 = off_pt + (size_t)125 * M_QUERY * 2 * 4;
  if (ws_size < need125) return;
  const bool use250 = (ws_size >= need250);

  unsigned short* tbp = (unsigned short*)(ws + off_tb);
  unsigned short* qb  = (unsigned short*)(ws + off_qb);
  float* tsq = (float*)(ws + off_tsq);
  float* qsq = (float*)(ws + off_qsq);
  float* part = (float*)(ws + off_pt);

  hipLaunchKernelGGL(convert_kernel, dim3((N_TRAIN * 8) / 256), dim3(256), 0, stream,
                     train, tbp, tsq, N_TRAIN, 1.0f);
  hipLaunchKernelGGL(convert_kernel, dim3((M_QUERY * 8) / 256), dim3(256), 0, stream,
                     test, qb, qsq, M_QUERY, -2.0f);
  if (use250) {
    hipLaunchKernelGGL(knn_main<250>, dim3(250 * 8), dim3(256), 0, stream,
                       tbp, qb, tsq, part);
    hipLaunchKernelGGL(knn_reduce, dim3(M_QUERY / 256), dim3(256), 0, stream,
                       part, qsq, out, 250);
  } else {
    hipLaunchKernelGGL(knn_main<125>, dim3(125 * 8), dim3(256), 0, stream,
                       tbp, qb, tsq, part);
    hipLaunchKernelGGL(knn_reduce, dim3(M_QUERY / 256), dim3(256), 0, stream,
                       part, qsq, out, 125);
  }
}

// Round 7
// 193.346 us; speedup vs baseline: 1.5367x; 1.5367x over previous
//
#include <hip/hip_runtime.h>
#include <hip/hip_bf16.h>

// 2-NN: out[q] = sum of 2 smallest ||q - t||^2 over 200000 train points.
// d2 = q_sq + t_sq - 2*q.t ; top-2 depends only on s = t_sq - 2*q.t.
// v7 = r4's proven gll+dbuf+syncthreads structure, plus (isolated deltas):
//   - XCD block remap (r5-proven: FETCH 204->28 MB, chunk L2-resident)
//   - TB=64, NCH=125: 2x MFMA per barrier interval; 4 blocks/CU (LDS 39 KB)
//   - queries pre-scaled by -2; t_sq injected via MFMA C-in (r5-proven)
// No setprio / sched_barrier / counted vmcnt (r5/r6 showed they regressed here).

typedef short bf16x8 __attribute__((ext_vector_type(8)));   // 8 bf16 = 4 VGPRs
typedef float f32x4 __attribute__((ext_vector_type(4)));

#define N_TRAIN 200000
#define M_QUERY 2048
#define DIMS 128
#define TB 64                     // train points per pipeline tile (16 KB)

__device__ __forceinline__ unsigned int bf_bits(float f) {
  unsigned int u = __float_as_uint(f);
  return (u + 0x7FFFu + ((u >> 16) & 1u)) >> 16;
}

// 8 lanes per row; each lane handles 16 contiguous floats (64B) -> coalesced.
// dst holds bf16(scale * src); sq holds exact fp32 ||row||^2 of UNSCALED src.
__global__ __launch_bounds__(256) void convert_kernel(
    const float* __restrict__ src, unsigned short* __restrict__ dst,
    float* __restrict__ sq, int nrows, float scale) {
  int gtid = blockIdx.x * 256 + threadIdx.x;
  int row = gtid >> 3, sub = gtid & 7;
  if (row >= nrows) return;
  const float4* s4 = reinterpret_cast<const float4*>(src + (size_t)row * DIMS + sub * 16);
  unsigned int pk[8];
  float acc = 0.f;
#pragma unroll
  for (int i = 0; i < 4; ++i) {
    float4 v = s4[i];
    acc += v.x * v.x + v.y * v.y + v.z * v.z + v.w * v.w;
    pk[i * 2 + 0] = bf_bits(v.x * scale) | (bf_bits(v.y * scale) << 16);
    pk[i * 2 + 1] = bf_bits(v.z * scale) | (bf_bits(v.w * scale) << 16);
  }
  uint4* d4 = reinterpret_cast<uint4*>(dst + (size_t)row * DIMS + sub * 16);
  d4[0] = make_uint4(pk[0], pk[1], pk[2], pk[3]);
  d4[1] = make_uint4(pk[4], pk[5], pk[6], pk[7]);
  acc += __shfl_xor(acc, 1);
  acc += __shfl_xor(acc, 2);
  acc += __shfl_xor(acc, 4);
  if (sub == 0) sq[row] = acc;
}

// Main. Block = 4 waves; wave owns 64 queries (4 m-tiles of 16).
// Block remap: xcd = b&7 (HW round-robin); the 8 qblocks of a chunk share an XCD.
template <int NCH>
__global__ __launch_bounds__(256) void knn_main(
    const unsigned short* __restrict__ tb, const unsigned short* __restrict__ qb16,
    const float* __restrict__ tsq, float* __restrict__ partials) {
  constexpr int PPC = N_TRAIN / NCH;        // 1600
  constexpr int ITERS = PPC / TB;           // 25
  const int b = blockIdx.x;
  const int g = (b & 7) * NCH + (b >> 3);   // same-xcd blocks: consecutive g
  const int chunk = g >> 3;
  const int qblock = (g & 7) << 8;
  const int tid = threadIdx.x;
  const int w = tid >> 6, l = tid & 63;
  const int lo = l & 15, hi = l >> 4;
  const int qw = qblock + w * 64;

  __shared__ char smem[2 * 16384];          // double-buffered 16 KB tiles
  __shared__ float tsq_s[PPC];              // chunk's t_sq (6.4 KB)

  // A-fragments (hold -2*q in bf16): Q[qw + t*16 + lo][kf*32 + hi*8 .. +8]
  bf16x8 a[4][4];
#pragma unroll
  for (int t = 0; t < 4; ++t)
#pragma unroll
    for (int kf = 0; kf < 4; ++kf)
      a[t][kf] = *reinterpret_cast<const bf16x8*>(
          qb16 + (size_t)(qw + t * 16 + lo) * DIMS + kf * 32 + hi * 8);

  // t_sq chunk into LDS
  for (int i = tid; i < PPC; i += 256) tsq_s[i] = tsq[chunk * PPC + i];

  // gll staging: LDS dest linear (wave base + lane*16); global source
  // pre-swizzled so LDS[(row, blk)] = global(row, blk ^ (row&7)).
  // Thread covers rows srow, srow+16, srow+32, srow+48 (same row&7 -> same
  // swizzle), i.e. LDS offsets tid*16 + {0,4096,8192,12288}.
  const int srow = tid >> 4, sblk = tid & 15;
  const char* gsrc = reinterpret_cast<const char*>(tb) +
                     (size_t)chunk * PPC * 256 + srow * 256 + ((sblk ^ (srow & 7)) << 4);
  char* lbase = smem + w * 1024;            // wave-uniform base (lane adds l*16)

  // ds_read offsets: point p = 16*half + lo, block kb = kf*4+hi:
  // addr = p*256 + ((kb ^ (p&7)) << 4); half adds 4096.
  int roff[4];
#pragma unroll
  for (int kf = 0; kf < 4; ++kf)
    roff[kf] = lo * 256 + ((((kf << 2) + hi) ^ (lo & 7)) << 4);

  const float INF = __builtin_inff();
  float best1[4][4], best2[4][4];
#pragma unroll
  for (int t = 0; t < 4; ++t)
#pragma unroll
    for (int r = 0; r < 4; ++r) { best1[t][r] = INF; best2[t][r] = INF; }

  // prologue: stage tile 0 into buffer 0
#pragma unroll
  for (int s = 0; s < 4; ++s)
    __builtin_amdgcn_global_load_lds(
        (const __attribute__((address_space(1))) void*)(gsrc + s * 4096),
        (__attribute__((address_space(3))) void*)(lbase + s * 4096), 16, 0, 0);
  gsrc += TB * 256;
  __syncthreads();

  int cur = 0;
  for (int it = 0; it < ITERS; ++it) {
    if (it + 1 < ITERS) {  // async-stage next tile into the other buffer
      char* nb = lbase + ((cur ^ 1) << 14);
#pragma unroll
      for (int s = 0; s < 4; ++s)
        __builtin_amdgcn_global_load_lds(
            (const __attribute__((address_space(1))) void*)(gsrc + s * 4096),
            (__attribute__((address_space(3))) void*)(nb + s * 4096), 16, 0, 0);
      gsrc += TB * 256;
    }

    const char* buf = smem + (cur << 14);
#pragma unroll
    for (int half = 0; half < 4; ++half) {
      bf16x8 f[4];
#pragma unroll
      for (int kf = 0; kf < 4; ++kf)
        f[kf] = *reinterpret_cast<const bf16x8*>(buf + roff[kf] + half * 4096);
      float tv = tsq_s[it * TB + half * 16 + lo];
      f32x4 c = {tv, tv, tv, tv};
#pragma unroll
      for (int t = 0; t < 4; ++t) {
        f32x4 acc = __builtin_amdgcn_mfma_f32_16x16x32_bf16(a[t][0], f[0], c, 0, 0, 0);
        acc = __builtin_amdgcn_mfma_f32_16x16x32_bf16(a[t][1], f[1], acc, 0, 0, 0);
        acc = __builtin_amdgcn_mfma_f32_16x16x32_bf16(a[t][2], f[2], acc, 0, 0, 0);
        acc = __builtin_amdgcn_mfma_f32_16x16x32_bf16(a[t][3], f[3], acc, 0, 0, 0);
#pragma unroll
        for (int r = 0; r < 4; ++r) {
          float s0 = acc[r];                // = t_sq - 2 q.t  (C-in carried t_sq)
          float n1 = fminf(best1[t][r], s0);
          float n2 = __builtin_amdgcn_fmed3f(best1[t][r], best2[t][r], s0);
          best1[t][r] = n1;
          best2[t][r] = n2;
        }
      }
    }
    __syncthreads();   // drains gll for next tile; cur-buf reads complete
    cur ^= 1;
  }

  // merge top-2 across the 16 lanes (columns) sharing each query
#pragma unroll
  for (int t = 0; t < 4; ++t)
#pragma unroll
    for (int r = 0; r < 4; ++r) {
      float v1 = best1[t][r], v2 = best2[t][r];
#pragma unroll
      for (int m = 1; m < 16; m <<= 1) {
        float o1 = __shfl_xor(v1, m);
        float o2 = __shfl_xor(v2, m);
        float n1 = fminf(v1, o1);
        float n2 = fminf(fmaxf(v1, o1), fminf(v2, o2));
        v1 = n1;
        v2 = n2;
      }
      best1[t][r] = v1;
      best2[t][r] = v2;
    }
  if (lo == 0) {
#pragma unroll
    for (int t = 0; t < 4; ++t)
#pragma unroll
      for (int r = 0; r < 4; ++r) {
        int q = qw + t * 16 + hi * 4 + r;
        float* p = partials + ((size_t)chunk * M_QUERY + q) * 2;
        p[0] = best1[t][r];
        p[1] = best2[t][r];
      }
  }
}

__global__ __launch_bounds__(256) void knn_reduce(
    const float* __restrict__ partials, const float* __restrict__ qsq,
    float* __restrict__ out, int nchunk) {
  int q = blockIdx.x * 256 + threadIdx.x;
  if (q >= M_QUERY) return;
  const float INF = __builtin_inff();
  float b1 = INF, b2 = INF;
  for (int c = 0; c < nchunk; ++c) {
    const float* p = partials + ((size_t)c * M_QUERY + q) * 2;
    float v = p[0];
    float n1 = fminf(b1, v);
    float n2 = __builtin_amdgcn_fmed3f(b1, b2, v);
    b1 = n1; b2 = n2;
    v = p[1];
    n1 = fminf(b1, v);
    n2 = __builtin_amdgcn_fmed3f(b1, b2, v);
    b1 = n1; b2 = n2;
  }
  out[q] = 2.f * qsq[q] + b1 + b2;
}

extern "C" void kernel_launch(void* const* d_in, const int* in_sizes, int n_in,
                              void* d_out, int out_size, void* d_ws, size_t ws_size,
                              hipStream_t stream) {
  const float* train = (const float*)d_in[0];  // 200000 x 128 f32
  const float* test  = (const float*)d_in[1];  // 2048 x 128 f32
  float* out = (float*)d_out;                  // 2048 f32
  char* ws = (char*)d_ws;

  size_t off_tb  = 0;                                      // train bf16: 51,200,000 B
  size_t off_qb  = off_tb  + (size_t)N_TRAIN * DIMS * 2;   // query bf16 (-2q)
  size_t off_tsq = off_qb  + (size_t)M_QUERY * DIMS * 2;   // t_sq
  size_t off_qsq = off_tsq + (size_t)N_TRAIN * 4;          // q_sq
  size_t off_pt  = off_qsq + (size_t)M_QUERY * 4;          // partials
  size_t need125 = off_pt + (size_t)125 * M_QUERY * 2 * 4;
  if (ws_size < need125) return;

  unsigned short* tbp = (unsigned short*)(ws + off_tb);
  unsigned short* qb  = (unsigned short*)(ws + off_qb);
  float* tsq = (float*)(ws + off_tsq);
  float* qsq = (float*)(ws + off_qsq);
  float* part = (float*)(ws + off_pt);

  hipLaunchKernelGGL(convert_kernel, dim3((N_TRAIN * 8) / 256), dim3(256), 0, stream,
                     train, tbp, tsq, N_TRAIN, 1.0f);
  hipLaunchKernelGGL(convert_kernel, dim3((M_QUERY * 8) / 256), dim3(256), 0, stream,
                     test, qb, qsq, M_QUERY, -2.0f);
  hipLaunchKernelGGL(knn_main<125>, dim3(125 * 8), dim3(256), 0, stream,
                     tbp, qb, tsq, part);
  hipLaunchKernelGGL(knn_reduce, dim3(M_QUERY / 256), dim3(256), 0, stream,
                     part, qsq, out, 125);
}